// Round 10
// baseline (1145.950 us; speedup 1.0000x reference)
//
#include <hip/hip_runtime.h>
#include <cstdint>
#include <cstddef>

typedef __bf16 bf16x8 __attribute__((ext_vector_type(8)));
typedef float f32x4 __attribute__((ext_vector_type(4)));
typedef unsigned short u16;

#define NB 8
#define NS 512
#define ND 768
#define NH 12
#define NL 6
#define NI 3072
#define NROWS (NB*NS)      // 4096
#define SD (NS*ND)         // 393216
#define MN ((size_t)NROWS*ND)  // 3145728

__device__ __forceinline__ u16 f2bf(float f) {
  union { float f; unsigned u; } v; v.f = f;
  unsigned r = v.u + 0x7fffu + ((v.u >> 16) & 1u);
  return (u16)(r >> 16);
}

#define GLL(gsrc, ldst) \
  __builtin_amdgcn_global_load_lds((__attribute__((address_space(1))) void*)(gsrc), \
                                   (__attribute__((address_space(3))) void*)(ldst), 16, 0, 0)

// ---------------- weight transpose+convert: src f32 [R][C] -> dst bf16 [C][R] ----------------
// Persistent variant: 648 blocks x 8 tile-jobs each (was 5184 one-shot blocks).
// Amortizes per-block fixed cost (setup + first-load latency + drain) 8x; job i+1's
// global loads issue while job i's stores drain. Jobs are tc-major -> consecutive jobs
// read the same 128 source rows (page locality).
#define CHS 4168   // u16 stride per 64x65 chunk (+8 pad)

__global__ __launch_bounds__(256) void wconv_k(
    const float* __restrict__ Wq, const float* __restrict__ Wk, const float* __restrict__ Wv,
    const float* __restrict__ W1, const float* __restrict__ Wi, const float* __restrict__ W2,
    u16* __restrict__ wqkv_t, u16* __restrict__ w1_t, u16* __restrict__ wi_t, u16* __restrict__ w2_t)
{
  __shared__ u16 lds[2 * CHS];
  int t0 = threadIdx.x;
  #pragma unroll 1
  for (int jj = 0; jj < 8; jj++) {
    int jid = blockIdx.x * 8 + jj;   // 0..5183
    int l = jid / 864, r = jid % 864;
    const float* src; u16* dst; int Csrc, dstLD, tr, tc;
    if (r < 216) {
      int which = r / 72, t2 = r % 72;
      src = (which == 0 ? Wq : (which == 1 ? Wk : Wv)) + (size_t)l * ND * ND;
      dst = wqkv_t + (size_t)l * 2304 * ND + (size_t)which * ND * ND;
      Csrc = ND; dstLD = ND; tr = t2 / 12; tc = t2 % 12;
    } else if (r < 288) {
      int t2 = r - 216;
      src = W1 + (size_t)l * ND * ND; dst = w1_t + (size_t)l * ND * ND;
      Csrc = ND; dstLD = ND; tr = t2 / 12; tc = t2 % 12;
    } else if (r < 576) {
      int t2 = r - 288;
      src = Wi + (size_t)l * ND * NI; dst = wi_t + (size_t)l * ND * NI;
      Csrc = NI; dstLD = ND; tr = t2 / 48; tc = t2 % 48;
    } else {
      int t2 = r - 576;
      src = W2 + (size_t)l * ND * NI; dst = w2_t + (size_t)l * ND * NI;
      Csrc = ND; dstLD = NI; tr = t2 / 12; tc = t2 % 12;
    }
    // load phase (issues before barrier; overlaps previous job's stores)
    int rrow = t0 >> 3, c0 = (t0 & 7) * 8;
    float4 va[4], vb[4];
    #pragma unroll
    for (int q = 0; q < 4; q++) {
      const float* sp = src + (size_t)(tr * 128 + q * 32 + rrow) * Csrc + tc * 64 + c0;
      va[q] = *reinterpret_cast<const float4*>(sp);
      vb[q] = *reinterpret_cast<const float4*>(sp + 4);
    }
    __syncthreads();   // previous job's LDS reads complete
    #pragma unroll
    for (int q = 0; q < 4; q++) {
      int row = q * 32 + rrow;
      u16* lp = &lds[(row >> 6) * CHS + (row & 63) * 65 + c0];
      lp[0] = f2bf(va[q].x); lp[1] = f2bf(va[q].y); lp[2] = f2bf(va[q].z); lp[3] = f2bf(va[q].w);
      lp[4] = f2bf(vb[q].x); lp[5] = f2bf(vb[q].y); lp[6] = f2bf(vb[q].z); lp[7] = f2bf(vb[q].w);
    }
    __syncthreads();   // LDS tile ready
    int qq = t0 & 15;
    int rb = t0 >> 4;
    int ch = qq >> 3;
    int r6b = (qq & 7) * 8;
    #pragma unroll
    for (int p = 0; p < 4; p++) {
      int dstrow = p * 16 + rb;
      const u16* lq = &lds[ch * CHS + dstrow];
      unsigned res[4];
      #pragma unroll
      for (int e = 0; e < 4; e++) {
        unsigned lo = lq[(r6b + 2 * e) * 65];
        unsigned hi = lq[(r6b + 2 * e + 1) * 65];
        res[e] = lo | (hi << 16);
      }
      u16* dp = dst + (size_t)(tc * 64 + dstrow) * dstLD + tr * 128 + qq * 8;
      *reinterpret_cast<uint4*>(dp) = make_uint4(res[0], res[1], res[2], res[3]);
    }
  }
}

// ---------------- embedding sum -> f32 ----------------
__global__ void embed_k(const int* __restrict__ ids, const int* __restrict__ segs,
    const float* __restrict__ wemb, const float* __restrict__ semb, const float* __restrict__ pemb,
    float* __restrict__ out)
{
  int row = blockIdx.x;
  int s = row & (NS - 1);
  int t = threadIdx.x;
  int id = ids[row], sg = segs[row];
  float4 a = reinterpret_cast<const float4*>(wemb + (size_t)id * ND)[t];
  float4 b = reinterpret_cast<const float4*>(semb + (size_t)sg * ND)[t];
  float4 c = reinterpret_cast<const float4*>(pemb + (size_t)s * ND)[t];
  float4 o;
  o.x = a.x + b.x + c.x; o.y = a.y + b.y + c.y; o.z = a.z + b.z + c.z; o.w = a.w + b.w + c.w;
  reinterpret_cast<float4*>(out + (size_t)row * ND)[t] = o;
}

// ---------------- LayerNorm partial sums over (S,D) per batch ----------------
__global__ __launch_bounds__(256) void ln_part_k(const float* __restrict__ x, float* __restrict__ part)
{
  int b = blockIdx.x >> 6, c = blockIdx.x & 63;
  const float* base = x + (size_t)b * SD + c * 6144;
  int t = threadIdx.x;
  float s = 0.f, sq = 0.f;
  #pragma unroll
  for (int j = 0; j < 6; j++) {
    float4 v = reinterpret_cast<const float4*>(base)[t + j * 256];
    s += v.x + v.y + v.z + v.w;
    sq += v.x * v.x + v.y * v.y + v.z * v.z + v.w * v.w;
  }
  #pragma unroll
  for (int d = 1; d < 64; d <<= 1) { s += __shfl_xor(s, d); sq += __shfl_xor(sq, d); }
  __shared__ float red[8];
  int w = t >> 6, lane = t & 63;
  if (lane == 0) { red[w] = s; red[4 + w] = sq; }
  __syncthreads();
  if (t == 0) {
    part[blockIdx.x * 2 + 0] = red[0] + red[1] + red[2] + red[3];
    part[blockIdx.x * 2 + 1] = red[4] + red[5] + red[6] + red[7];
  }
}

// ---------------- LN apply (fused final reduce of part[]) ----------------
__global__ __launch_bounds__(256) void ln_apply_k(const float* __restrict__ x,
    const float* __restrict__ g, const float* __restrict__ bta, const float* __restrict__ part,
    float* __restrict__ xf, u16* __restrict__ xb)
{
  int idx = blockIdx.x * 256 + threadIdx.x;
  int e = idx * 4;
  int b = e / SD;
  int sd = e - b * SD;
  int lane = threadIdx.x & 63;
  float s = part[b * 128 + lane * 2 + 0];
  float q = part[b * 128 + lane * 2 + 1];
  #pragma unroll
  for (int d = 1; d < 64; d <<= 1) { s += __shfl_xor(s, d); q += __shfl_xor(q, d); }
  float inv = 1.f / (float)SD;
  float mu = s * inv;
  float rstd = rsqrtf(q * inv - mu * mu + 1e-5f);
  float4 v = reinterpret_cast<const float4*>(x)[idx];
  float4 gg = reinterpret_cast<const float4*>(g)[sd >> 2];
  float4 bb = reinterpret_cast<const float4*>(bta)[sd >> 2];
  float y0 = (v.x - mu) * rstd * gg.x + bb.x;
  float y1 = (v.y - mu) * rstd * gg.y + bb.y;
  float y2 = (v.z - mu) * rstd * gg.z + bb.z;
  float y3 = (v.w - mu) * rstd * gg.w + bb.w;
  float4 o; o.x = y0; o.y = y1; o.z = y2; o.w = y3;
  reinterpret_cast<float4*>(xf)[idx] = o;
  reinterpret_cast<ushort4*>(xb)[idx] = make_ushort4(f2bf(y0), f2bf(y1), f2bf(y2), f2bf(y3));
}

// ---------------- W1 finalize: sum 4 K-partials + bias, relu -> bf16 ----------------
__global__ __launch_bounds__(256) void finw1_k(const float* __restrict__ P,
    const float* __restrict__ bias, u16* __restrict__ out)
{
  size_t idx = (size_t)blockIdx.x * 256 + threadIdx.x;
  float4 p0 = reinterpret_cast<const float4*>(P)[idx];
  float4 p1 = reinterpret_cast<const float4*>(P)[idx + (MN >> 2)];
  float4 p2 = reinterpret_cast<const float4*>(P)[idx + 2 * (MN >> 2)];
  float4 p3 = reinterpret_cast<const float4*>(P)[idx + 3 * (MN >> 2)];
  int col4 = (int)((idx * 4) % ND) >> 2;
  float4 bv = reinterpret_cast<const float4*>(bias)[col4];
  float y0 = fmaxf(p0.x + p1.x + p2.x + p3.x + bv.x, 0.f);
  float y1 = fmaxf(p0.y + p1.y + p2.y + p3.y + bv.y, 0.f);
  float y2 = fmaxf(p0.z + p1.z + p2.z + p3.z + bv.z, 0.f);
  float y3 = fmaxf(p0.w + p1.w + p2.w + p3.w + bv.w, 0.f);
  reinterpret_cast<ushort4*>(out)[idx] = make_ushort4(f2bf(y0), f2bf(y1), f2bf(y2), f2bf(y3));
}

// ---------------- W2 finalize: sum 4 K-partials + bias, relu, +resid -> ln_in, fused LN partial ----
__global__ __launch_bounds__(256) void finw2_k(const float* __restrict__ P,
    const float* __restrict__ bias, const float* __restrict__ resid,
    float* __restrict__ ln_in, float* __restrict__ part)
{
  int b = blockIdx.x >> 6, c = blockIdx.x & 63;
  size_t f4base = ((size_t)b * SD + (size_t)c * 6144) >> 2;
  int t = threadIdx.x;
  float s = 0.f, sq = 0.f;
  #pragma unroll
  for (int j = 0; j < 6; j++) {
    size_t fi = f4base + t + j * 256;
    float4 p0 = reinterpret_cast<const float4*>(P)[fi];
    float4 p1 = reinterpret_cast<const float4*>(P)[fi + (MN >> 2)];
    float4 p2 = reinterpret_cast<const float4*>(P)[fi + 2 * (MN >> 2)];
    float4 p3 = reinterpret_cast<const float4*>(P)[fi + 3 * (MN >> 2)];
    float4 rv = reinterpret_cast<const float4*>(resid)[fi];
    int col4 = (((t + j * 256) * 4) % ND) >> 2;
    float4 bv = reinterpret_cast<const float4*>(bias)[col4];
    float y0 = fmaxf(p0.x + p1.x + p2.x + p3.x + bv.x, 0.f) + rv.x;
    float y1 = fmaxf(p0.y + p1.y + p2.y + p3.y + bv.y, 0.f) + rv.y;
    float y2 = fmaxf(p0.z + p1.z + p2.z + p3.z + bv.z, 0.f) + rv.z;
    float y3 = fmaxf(p0.w + p1.w + p2.w + p3.w + bv.w, 0.f) + rv.w;
    float4 o; o.x = y0; o.y = y1; o.z = y2; o.w = y3;
    reinterpret_cast<float4*>(ln_in)[fi] = o;
    s += y0 + y1 + y2 + y3;
    sq += y0 * y0 + y1 * y1 + y2 * y2 + y3 * y3;
  }
  #pragma unroll
  for (int d = 1; d < 64; d <<= 1) { s += __shfl_xor(s, d); sq += __shfl_xor(sq, d); }
  __shared__ float red[8];
  int w = t >> 6, lane = t & 63;
  if (lane == 0) { red[w] = s; red[4 + w] = sq; }
  __syncthreads();
  if (t == 0) {
    part[blockIdx.x * 2 + 0] = red[0] + red[1] + red[2] + red[3];
    part[blockIdx.x * 2 + 1] = red[4] + red[5] + red[6] + red[7];
  }
}

// ---------------- GEMM: C[M][N] = A[M][K] * Bt[N][K]^T  (bf16 in, f32 acc) ----------------
// BM=BN=128, BK=32, 2-phase dbuf, 4 waves each 64x64 out.
// EPI 0: store bf16. EPI 1: relu(acc+bias) bf16. EPI 3: f32 partial (split-K via blockIdx.z).
#define BM 128
#define BN 128
#define BK 32

template<int EPI>
__global__ __launch_bounds__(256) void gemm_bt(
    const u16* __restrict__ A, const u16* __restrict__ Bt, void* __restrict__ Cv,
    const float* __restrict__ bias, int M, int N, int K)
{
  __shared__ __align__(16) u16 As[2][BM * BK];
  __shared__ __align__(16) u16 Bs[2][BN * BK];
  const int t = threadIdx.x;
  const int lane = t & 63, w = t >> 6;
  const int wr = w >> 1, wc = w & 1;
  const int l15 = lane & 15, lh = lane >> 4;
  const int m0 = blockIdx.y * BM, n0 = blockIdx.x * BN;
  const int Ksub = K / gridDim.z;
  const int Koff = blockIdx.z * Ksub;

  f32x4 acc[4][4];
  const f32x4 z4 = {0.f, 0.f, 0.f, 0.f};
  #pragma unroll
  for (int i = 0; i < 4; i++)
    #pragma unroll
    for (int j = 0; j < 4; j++) acc[i][j] = z4;

  const int ca = t, cb = t + 256;
  const u16* a0p = A + (size_t)(m0 + (ca >> 2)) * K + (ca & 3) * 8 + Koff;
  const u16* a1p = A + (size_t)(m0 + (cb >> 2)) * K + (cb & 3) * 8 + Koff;
  const u16* b0p = Bt + (size_t)(n0 + (ca >> 2)) * K + (ca & 3) * 8 + Koff;
  const u16* b1p = Bt + (size_t)(n0 + (cb >> 2)) * K + (cb & 3) * 8 + Koff;

  auto stage = [&](int buf, int k0) {
    GLL(a0p + k0, &As[buf][ca * 8]);
    GLL(a1p + k0, &As[buf][cb * 8]);
    GLL(b0p + k0, &Bs[buf][ca * 8]);
    GLL(b1p + k0, &Bs[buf][cb * 8]);
  };

  const int nt = Ksub / BK;
  stage(0, 0);
  __syncthreads();
  for (int it = 0; it < nt; ++it) {
    const int cur = it & 1;
    if (it + 1 < nt) stage(cur ^ 1, (it + 1) * BK);
    bf16x8 af[4], bfr[4];
    #pragma unroll
    for (int i = 0; i < 4; i++)
      af[i] = *reinterpret_cast<const bf16x8*>(&As[cur][(wr * 64 + i * 16 + l15) * BK + lh * 8]);
    #pragma unroll
    for (int j = 0; j < 4; j++)
      bfr[j] = *reinterpret_cast<const bf16x8*>(&Bs[cur][(wc * 64 + j * 16 + l15) * BK + lh * 8]);
    #pragma unroll
    for (int i = 0; i < 4; i++)
      #pragma unroll
      for (int j = 0; j < 4; j++)
        acc[i][j] = __builtin_amdgcn_mfma_f32_16x16x32_bf16(af[i], bfr[j], acc[i][j], 0, 0, 0);
    __syncthreads();
  }

  float* Pout = (float*)Cv + (size_t)blockIdx.z * M * N;
  #pragma unroll
  for (int i = 0; i < 4; i++) {
    int row_b = m0 + wr * 64 + i * 16 + lh * 4;
    #pragma unroll
    for (int j = 0; j < 4; j++) {
      int col = n0 + wc * 64 + j * 16 + l15;
      float bv = (EPI == 1) ? bias[col] : 0.f;
      #pragma unroll
      for (int r = 0; r < 4; r++) {
        size_t off = (size_t)(row_b + r) * N + col;
        float v = acc[i][j][r];
        if (EPI == 1) ((u16*)Cv)[off] = f2bf(fmaxf(v + bv, 0.f));
        else if (EPI == 3) Pout[off] = v;
        else ((u16*)Cv)[off] = f2bf(v);
      }
    }
  }
}

// ---------------- fused attention (flash-style, online softmax), QBLK=64 ----------------
// qkv: [4096][2304] bf16 (q | k | v). out: [4096][768] bf16.
__global__ __launch_bounds__(256) void attn_k(
    const u16* __restrict__ qkv, const float* __restrict__ mask, u16* __restrict__ out)
{
  const int qt = blockIdx.x;   // 0..7 (64 q rows each)
  const int h = blockIdx.y;    // 0..11
  const int b = blockIdx.z;    // 0..7
  __shared__ __align__(16) u16 Qs[64 * 64];
  __shared__ __align__(16) u16 Ks[64 * 72];
  __shared__ __align__(16) u16 Vt[64 * 72];
  __shared__ __align__(16) u16 Pw[4][16 * 72];
  const int t = threadIdx.x, lane = t & 63, w = t >> 6;
  const int l15 = lane & 15, lh = lane >> 4;

  #pragma unroll
  for (int p = 0; p < 2; p++) {
    int c = t + p * 256;
    const u16* src = qkv + (size_t)(b * NS + qt * 64 + (c >> 3)) * 2304 + h * 64 + (c & 7) * 8;
    GLL(src, Qs + c * 8);
  }
  __syncthreads();

  bf16x8 aq[2];
  #pragma unroll
  for (int kk = 0; kk < 2; kk++)
    aq[kk] = *reinterpret_cast<const bf16x8*>(&Qs[(w * 16 + l15) * 64 + kk * 32 + lh * 8]);

  float qm[4];
  #pragma unroll
  for (int r = 0; r < 4; r++)
    qm[r] = mask[b * NS + qt * 64 + w * 16 + lh * 4 + r] * 0.125f;

  float mrun[4], lrun[4];
  f32x4 o[4];
  const f32x4 z4 = {0.f, 0.f, 0.f, 0.f};
  #pragma unroll
  for (int r = 0; r < 4; r++) { mrun[r] = -3e38f; lrun[r] = 0.f; }
  #pragma unroll
  for (int jn = 0; jn < 4; jn++) o[jn] = z4;

  for (int kc = 0; kc < 8; kc++) {
    __syncthreads();
    #pragma unroll
    for (int p = 0; p < 2; p++) {
      int k = (t >> 3) + p * 32;
      int dh0 = (t & 7) * 8;
      const u16* ks = qkv + (size_t)(b * NS + kc * 64 + k) * 2304 + ND + h * 64 + dh0;
      uint4 kv4 = *reinterpret_cast<const uint4*>(ks);
      *reinterpret_cast<uint4*>(&Ks[k * 72 + dh0]) = kv4;
    }
    #pragma unroll
    for (int p = 0; p < 2; p++) {
      int k = (t >> 3) + p * 32;
      int dh0 = (t & 7) * 8;
      const u16* vs = qkv + (size_t)(b * NS + kc * 64 + k) * 2304 + 2 * ND + h * 64 + dh0;
      uint4 vv = *reinterpret_cast<const uint4*>(vs);
      Vt[(dh0 + 0) * 72 + k] = (u16)(vv.x & 0xffff);
      Vt[(dh0 + 1) * 72 + k] = (u16)(vv.x >> 16);
      Vt[(dh0 + 2) * 72 + k] = (u16)(vv.y & 0xffff);
      Vt[(dh0 + 3) * 72 + k] = (u16)(vv.y >> 16);
      Vt[(dh0 + 4) * 72 + k] = (u16)(vv.z & 0xffff);
      Vt[(dh0 + 5) * 72 + k] = (u16)(vv.z >> 16);
      Vt[(dh0 + 6) * 72 + k] = (u16)(vv.w & 0xffff);
      Vt[(dh0 + 7) * 72 + k] = (u16)(vv.w >> 16);
    }
    __syncthreads();

    f32x4 s[4];
    #pragma unroll
    for (int j = 0; j < 4; j++) s[j] = z4;
    #pragma unroll
    for (int kk = 0; kk < 2; kk++) {
      bf16x8 bk[4];
      #pragma unroll
      for (int j = 0; j < 4; j++)
        bk[j] = *reinterpret_cast<const bf16x8*>(&Ks[(j * 16 + l15) * 72 + kk * 32 + lh * 8]);
      #pragma unroll
      for (int j = 0; j < 4; j++)
        s[j] = __builtin_amdgcn_mfma_f32_16x16x32_bf16(aq[kk], bk[j], s[j], 0, 0, 0);
    }

    #pragma unroll
    for (int r = 0; r < 4; r++) {
      float q4 = qm[r];
      float v0 = s[0][r] * q4, v1 = s[1][r] * q4, v2 = s[2][r] * q4, v3 = s[3][r] * q4;
      float pm = fmaxf(fmaxf(v0, v1), fmaxf(v2, v3));
      pm = fmaxf(pm, __shfl_xor(pm, 1));
      pm = fmaxf(pm, __shfl_xor(pm, 2));
      pm = fmaxf(pm, __shfl_xor(pm, 4));
      pm = fmaxf(pm, __shfl_xor(pm, 8));
      float mnew = fmaxf(mrun[r], pm);
      float corr = __expf(mrun[r] - mnew);
      mrun[r] = mnew;
      float p0 = __expf(v0 - mnew), p1 = __expf(v1 - mnew);
      float p2 = __expf(v2 - mnew), p3 = __expf(v3 - mnew);
      s[0][r] = p0; s[1][r] = p1; s[2][r] = p2; s[3][r] = p3;
      float rs = p0 + p1 + p2 + p3;
      rs += __shfl_xor(rs, 1);
      rs += __shfl_xor(rs, 2);
      rs += __shfl_xor(rs, 4);
      rs += __shfl_xor(rs, 8);
      lrun[r] = lrun[r] * corr + rs;
      #pragma unroll
      for (int jn = 0; jn < 4; jn++) o[jn][r] *= corr;
    }
    #pragma unroll
    for (int j = 0; j < 4; j++)
      #pragma unroll
      for (int r = 0; r < 4; r++)
        Pw[w][(lh * 4 + r) * 72 + j * 16 + l15] = f2bf(s[j][r]);

    #pragma unroll
    for (int kk2 = 0; kk2 < 2; kk2++) {
      bf16x8 pa, vb[4];
      pa = *reinterpret_cast<const bf16x8*>(&Pw[w][l15 * 72 + kk2 * 32 + lh * 8]);
      #pragma unroll
      for (int jn = 0; jn < 4; jn++)
        vb[jn] = *reinterpret_cast<const bf16x8*>(&Vt[(jn * 16 + l15) * 72 + kk2 * 32 + lh * 8]);
      #pragma unroll
      for (int jn = 0; jn < 4; jn++)
        o[jn] = __builtin_amdgcn_mfma_f32_16x16x32_bf16(pa, vb[jn], o[jn], 0, 0, 0);
    }
  }

  #pragma unroll
  for (int r = 0; r < 4; r++) {
    int q = qt * 64 + w * 16 + lh * 4 + r;
    float invl = 1.f / lrun[r];
    #pragma unroll
    for (int jn = 0; jn < 4; jn++) {
      int col = h * 64 + jn * 16 + l15;
      out[(size_t)(b * NS + q) * ND + col] = f2bf(o[jn][r] * invl);
    }
  }
}

// ---------------- final logits ----------------
__global__ __launch_bounds__(256) void logits_k(const float* __restrict__ x,
    const float* __restrict__ Wp, const float* __restrict__ bp, const float* __restrict__ mask,
    float* __restrict__ out)
{
  int t = threadIdx.x, lane = t & 63, w = t >> 6;
  int row = blockIdx.x * 4 + w;
  const float* xr = x + (size_t)row * ND;
  float a0 = 0.f, a1 = 0.f;
  for (int i = lane; i < ND; i += 64) {
    float v = xr[i];
    a0 += v * Wp[i * 2 + 0];
    a1 += v * Wp[i * 2 + 1];
  }
  #pragma unroll
  for (int d = 1; d < 64; d <<= 1) { a0 += __shfl_xor(a0, d); a1 += __shfl_xor(a1, d); }
  if (lane == 0) {
    float pen = (1.f - mask[row]) * -10000.f;
    out[row] = a0 + bp[0] + pen;
    out[NROWS + row] = a1 + bp[1] + pen;
  }
}

extern "C" void kernel_launch(void* const* d_in, const int* in_sizes, int n_in,
                              void* d_out, int out_size, void* d_ws, size_t ws_size,
                              hipStream_t stream)
{
  const int* ids = (const int*)d_in[0];
  const int* segs = (const int*)d_in[1];
  const float* mask = (const float*)d_in[2];
  const float* wemb = (const float*)d_in[3];
  const float* semb = (const float*)d_in[4];
  const float* pemb = (const float*)d_in[5];
  const float* ln0g = (const float*)d_in[6];
  const float* ln0b = (const float*)d_in[7];
  const float* Wq = (const float*)d_in[8];
  const float* Wk = (const float*)d_in[9];
  const float* Wv = (const float*)d_in[10];
  const float* W1 = (const float*)d_in[11];
  const float* b1 = (const float*)d_in[12];
  const float* Wi = (const float*)d_in[13];
  const float* bi = (const float*)d_in[14];
  const float* W2 = (const float*)d_in[15];
  const float* b2 = (const float*)d_in[16];
  const float* lng = (const float*)d_in[17];
  const float* lnb = (const float*)d_in[18];
  const float* Wp = (const float*)d_in[19];
  const float* bp = (const float*)d_in[20];

  char* ws = (char*)d_ws;
  size_t o = 0;
  auto alloc = [&](size_t n) { size_t r = o; o += (n + 255) & ~(size_t)255; return r; };
  u16* wqkv_t = (u16*)(ws + alloc((size_t)NL * 2304 * ND * 2));
  u16* w1_t   = (u16*)(ws + alloc((size_t)NL * ND * ND * 2));
  u16* wi_t   = (u16*)(ws + alloc((size_t)NL * ND * NI * 2));
  u16* w2_t   = (u16*)(ws + alloc((size_t)NL * ND * NI * 2));
  float* x_f32 = (float*)(ws + alloc((size_t)NROWS * ND * 4));
  u16* x_bf16  = (u16*)(ws + alloc((size_t)NROWS * ND * 2));
  u16* qkv     = (u16*)(ws + alloc((size_t)NROWS * 2304 * 2));
  u16* attn    = (u16*)(ws + alloc((size_t)NROWS * ND * 2));
  u16* h1      = (u16*)(ws + alloc((size_t)NROWS * ND * 2));
  u16* hi      = (u16*)(ws + alloc((size_t)NROWS * NI * 2));
  float* ln_in = (float*)(ws + alloc((size_t)NROWS * ND * 4));
  float* pbuf  = (float*)(ws + alloc(4 * MN * 4));
  float* part  = (float*)(ws + alloc(512 * 2 * 4));

  wconv_k<<<648, 256, 0, stream>>>(Wq, Wk, Wv, W1, Wi, W2, wqkv_t, w1_t, wi_t, w2_t);
  embed_k<<<NROWS, 192, 0, stream>>>(ids, segs, wemb, semb, pemb, ln_in);
  ln_part_k<<<512, 256, 0, stream>>>(ln_in, part);
  ln_apply_k<<<3072, 256, 0, stream>>>(ln_in, ln0g, ln0b, part, x_f32, x_bf16);

  for (int l = 0; l < NL; l++) {
    gemm_bt<0><<<dim3(18, 32), 256, 0, stream>>>(x_bf16, wqkv_t + (size_t)l * 2304 * ND, qkv,
                                                 nullptr, NROWS, 2304, ND);
    attn_k<<<dim3(8, NH, NB), 256, 0, stream>>>(qkv, mask, attn);
    gemm_bt<3><<<dim3(6, 32, 4), 256, 0, stream>>>(attn, w1_t + (size_t)l * ND * ND, pbuf,
                                                   nullptr, NROWS, ND, ND);
    finw1_k<<<3072, 256, 0, stream>>>(pbuf, b1 + (size_t)l * ND, h1);
    gemm_bt<1><<<dim3(24, 32), 256, 0, stream>>>(h1, wi_t + (size_t)l * ND * NI, hi,
                                                 bi + (size_t)l * NI, NROWS, NI, ND);
    gemm_bt<3><<<dim3(6, 32, 4), 256, 0, stream>>>(hi, w2_t + (size_t)l * ND * NI, pbuf,
                                                   nullptr, NROWS, ND, NI);
    finw2_k<<<512, 256, 0, stream>>>(pbuf, b2 + (size_t)l * ND, x_f32, ln_in, part);
    ln_apply_k<<<3072, 256, 0, stream>>>(ln_in, lng + (size_t)l * SD, lnb + (size_t)l * SD, part, x_f32, x_bf16);
  }

  logits_k<<<1024, 256, 0, stream>>>(x_f32, Wp, bp, mask, (float*)d_out);
}

// Round 11
// 1114.519 us; speedup vs baseline: 1.0282x; 1.0282x over previous
//
#include <hip/hip_runtime.h>
#include <cstdint>
#include <cstddef>

typedef __bf16 bf16x8 __attribute__((ext_vector_type(8)));
typedef float f32x4 __attribute__((ext_vector_type(4)));
typedef unsigned short u16;

#define NB 8
#define NS 512
#define ND 768
#define NH 12
#define NL 6
#define NI 3072
#define NROWS (NB*NS)      // 4096
#define SD (NS*ND)         // 393216
#define MN ((size_t)NROWS*ND)  // 3145728

__device__ __forceinline__ u16 f2bf(float f) {
  union { float f; unsigned u; } v; v.f = f;
  unsigned r = v.u + 0x7fffu + ((v.u >> 16) & 1u);
  return (u16)(r >> 16);
}
__device__ __forceinline__ float b2f(u16 u) {
  union { unsigned u; float f; } v; v.u = ((unsigned)u) << 16; return v.f;
}

#define GLL(gsrc, ldst) \
  __builtin_amdgcn_global_load_lds((__attribute__((address_space(1))) void*)(gsrc), \
                                   (__attribute__((address_space(3))) void*)(ldst), 16, 0, 0)

// ---------------- weight transpose+convert (FROZEN at r9 variant: ~77us, structural ceiling
// for 255MB mixed read + 256B-segment transposed writes) ----------------
#define CHS 4168   // u16 stride per 64x65 chunk (+8 pad)

__global__ __launch_bounds__(256) void wconv_k(
    const float* __restrict__ Wq, const float* __restrict__ Wk, const float* __restrict__ Wv,
    const float* __restrict__ W1, const float* __restrict__ Wi, const float* __restrict__ W2,
    u16* __restrict__ wqkv_t, u16* __restrict__ w1_t, u16* __restrict__ wi_t, u16* __restrict__ w2_t)
{
  int bid = blockIdx.x;
  int l = bid / 864, r = bid % 864;
  const float* src; u16* dst; int Csrc, dstLD, tr, tc;
  if (r < 216) {
    int which = r / 72, t2 = r % 72;
    src = (which == 0 ? Wq : (which == 1 ? Wk : Wv)) + (size_t)l * ND * ND;
    dst = wqkv_t + (size_t)l * 2304 * ND + (size_t)which * ND * ND;
    Csrc = ND; dstLD = ND; tr = t2 / 12; tc = t2 % 12;
  } else if (r < 288) {
    int t2 = r - 216;
    src = W1 + (size_t)l * ND * ND; dst = w1_t + (size_t)l * ND * ND;
    Csrc = ND; dstLD = ND; tr = t2 / 12; tc = t2 % 12;
  } else if (r < 576) {
    int t2 = r - 288;
    src = Wi + (size_t)l * ND * NI; dst = wi_t + (size_t)l * ND * NI;
    Csrc = NI; dstLD = ND; tr = t2 / 48; tc = t2 % 48;
  } else {
    int t2 = r - 576;
    src = W2 + (size_t)l * ND * NI; dst = w2_t + (size_t)l * ND * NI;
    Csrc = ND; dstLD = NI; tr = t2 / 12; tc = t2 % 12;
  }
  __shared__ u16 lds[2 * CHS];
  int t0 = threadIdx.x;
  {
    int rrow = t0 >> 3, c0 = (t0 & 7) * 8;
    float4 va[4], vb[4];
    #pragma unroll
    for (int q = 0; q < 4; q++) {
      const float* sp = src + (size_t)(tr * 128 + q * 32 + rrow) * Csrc + tc * 64 + c0;
      va[q] = *reinterpret_cast<const float4*>(sp);
      vb[q] = *reinterpret_cast<const float4*>(sp + 4);
    }
    #pragma unroll
    for (int q = 0; q < 4; q++) {
      int row = q * 32 + rrow;
      u16* lp = &lds[(row >> 6) * CHS + (row & 63) * 65 + c0];
      lp[0] = f2bf(va[q].x); lp[1] = f2bf(va[q].y); lp[2] = f2bf(va[q].z); lp[3] = f2bf(va[q].w);
      lp[4] = f2bf(vb[q].x); lp[5] = f2bf(vb[q].y); lp[6] = f2bf(vb[q].z); lp[7] = f2bf(vb[q].w);
    }
  }
  __syncthreads();
  {
    int qq = t0 & 15;
    int rb = t0 >> 4;
    int ch = qq >> 3;
    int r6b = (qq & 7) * 8;
    #pragma unroll
    for (int p = 0; p < 4; p++) {
      int dstrow = p * 16 + rb;
      const u16* lq = &lds[ch * CHS + dstrow];
      unsigned res[4];
      #pragma unroll
      for (int e = 0; e < 4; e++) {
        unsigned lo = lq[(r6b + 2 * e) * 65];
        unsigned hi = lq[(r6b + 2 * e + 1) * 65];
        res[e] = lo | (hi << 16);
      }
      u16* dp = dst + (size_t)(tc * 64 + dstrow) * dstLD + tr * 128 + qq * 8;
      *reinterpret_cast<uint4*>(dp) = make_uint4(res[0], res[1], res[2], res[3]);
    }
  }
}

// ---------------- embedding sum -> f32, fused LN partial sums ----------------
// grid 512 = 8 batches x 64 chunks; chunk = 8 rows (6144 floats).
__global__ __launch_bounds__(256) void embed_ln_k(const int* __restrict__ ids,
    const int* __restrict__ segs, const float* __restrict__ wemb,
    const float* __restrict__ semb, const float* __restrict__ pemb,
    float* __restrict__ out, float* __restrict__ part)
{
  int b = blockIdx.x >> 6, c = blockIdx.x & 63;
  int base_row = b * NS + c * 8;
  int t = threadIdx.x;
  float s = 0.f, sq = 0.f;
  #pragma unroll
  for (int j = 0; j < 6; j++) {
    int fi = t + j * 256;               // 0..1535 (f4 within chunk)
    int riw = fi / 192, col4 = fi - riw * 192;
    int row = base_row + riw;
    int id = ids[row], sg = segs[row];
    int srow = row & (NS - 1);
    float4 a = reinterpret_cast<const float4*>(wemb + (size_t)id * ND)[col4];
    float4 bb = reinterpret_cast<const float4*>(semb + (size_t)sg * ND)[col4];
    float4 cc = reinterpret_cast<const float4*>(pemb + (size_t)srow * ND)[col4];
    float y0 = a.x + bb.x + cc.x, y1 = a.y + bb.y + cc.y;
    float y2 = a.z + bb.z + cc.z, y3 = a.w + bb.w + cc.w;
    float4 o; o.x = y0; o.y = y1; o.z = y2; o.w = y3;
    reinterpret_cast<float4*>(out)[(size_t)row * 192 + col4] = o;
    s += y0 + y1 + y2 + y3;
    sq += y0 * y0 + y1 * y1 + y2 * y2 + y3 * y3;
  }
  #pragma unroll
  for (int d = 1; d < 64; d <<= 1) { s += __shfl_xor(s, d); sq += __shfl_xor(sq, d); }
  __shared__ float red[8];
  int w = t >> 6, lane = t & 63;
  if (lane == 0) { red[w] = s; red[4 + w] = sq; }
  __syncthreads();
  if (t == 0) {
    part[blockIdx.x * 2 + 0] = red[0] + red[1] + red[2] + red[3];
    part[blockIdx.x * 2 + 1] = red[4] + red[5] + red[6] + red[7];
  }
}

// ---------------- LN apply (fused final reduce of part[]) -> bf16 only ----------------
__global__ __launch_bounds__(256) void ln_apply_k(const float* __restrict__ x,
    const float* __restrict__ g, const float* __restrict__ bta, const float* __restrict__ part,
    u16* __restrict__ xb)
{
  int idx = blockIdx.x * 256 + threadIdx.x;  // f4 index, 786432 total
  int e = idx * 4;
  int b = e / SD;
  int sd = e - b * SD;
  int lane = threadIdx.x & 63;
  float s = part[b * 128 + lane * 2 + 0];
  float q = part[b * 128 + lane * 2 + 1];
  #pragma unroll
  for (int d = 1; d < 64; d <<= 1) { s += __shfl_xor(s, d); q += __shfl_xor(q, d); }
  float inv = 1.f / (float)SD;
  float mu = s * inv;
  float rstd = rsqrtf(q * inv - mu * mu + 1e-5f);
  float4 v = reinterpret_cast<const float4*>(x)[idx];
  float4 gg = reinterpret_cast<const float4*>(g)[sd >> 2];
  float4 bb = reinterpret_cast<const float4*>(bta)[sd >> 2];
  float y0 = (v.x - mu) * rstd * gg.x + bb.x;
  float y1 = (v.y - mu) * rstd * gg.y + bb.y;
  float y2 = (v.z - mu) * rstd * gg.z + bb.z;
  float y3 = (v.w - mu) * rstd * gg.w + bb.w;
  reinterpret_cast<ushort4*>(xb)[idx] = make_ushort4(f2bf(y0), f2bf(y1), f2bf(y2), f2bf(y3));
}

// ---------------- W1 finalize: sum 4 K-partials + bias, relu -> bf16 ----------------
__global__ __launch_bounds__(256) void finw1_k(const float* __restrict__ P,
    const float* __restrict__ bias, u16* __restrict__ out)
{
  size_t idx = (size_t)blockIdx.x * 256 + threadIdx.x;
  float4 p0 = reinterpret_cast<const float4*>(P)[idx];
  float4 p1 = reinterpret_cast<const float4*>(P)[idx + (MN >> 2)];
  float4 p2 = reinterpret_cast<const float4*>(P)[idx + 2 * (MN >> 2)];
  float4 p3 = reinterpret_cast<const float4*>(P)[idx + 3 * (MN >> 2)];
  int col4 = (int)((idx * 4) % ND) >> 2;
  float4 bv = reinterpret_cast<const float4*>(bias)[col4];
  float y0 = fmaxf(p0.x + p1.x + p2.x + p3.x + bv.x, 0.f);
  float y1 = fmaxf(p0.y + p1.y + p2.y + p3.y + bv.y, 0.f);
  float y2 = fmaxf(p0.z + p1.z + p2.z + p3.z + bv.z, 0.f);
  float y3 = fmaxf(p0.w + p1.w + p2.w + p3.w + bv.w, 0.f);
  reinterpret_cast<ushort4*>(out)[idx] = make_ushort4(f2bf(y0), f2bf(y1), f2bf(y2), f2bf(y3));
}

// ---------------- W2 finalize: 4 partials + bias, relu, + bf16 resid -> ln_in f32, LN partial ----
__global__ __launch_bounds__(256) void finw2_k(const float* __restrict__ P,
    const float* __restrict__ bias, const u16* __restrict__ resid,
    float* __restrict__ ln_in, float* __restrict__ part)
{
  int b = blockIdx.x >> 6, c = blockIdx.x & 63;
  size_t f4base = ((size_t)b * SD + (size_t)c * 6144) >> 2;
  int t = threadIdx.x;
  float s = 0.f, sq = 0.f;
  #pragma unroll
  for (int j = 0; j < 6; j++) {
    size_t fi = f4base + t + j * 256;
    float4 p0 = reinterpret_cast<const float4*>(P)[fi];
    float4 p1 = reinterpret_cast<const float4*>(P)[fi + (MN >> 2)];
    float4 p2 = reinterpret_cast<const float4*>(P)[fi + 2 * (MN >> 2)];
    float4 p3 = reinterpret_cast<const float4*>(P)[fi + 3 * (MN >> 2)];
    ushort4 rv = reinterpret_cast<const ushort4*>(resid)[fi];
    int col4 = (((t + j * 256) * 4) % ND) >> 2;
    float4 bv = reinterpret_cast<const float4*>(bias)[col4];
    float y0 = fmaxf(p0.x + p1.x + p2.x + p3.x + bv.x, 0.f) + b2f(rv.x);
    float y1 = fmaxf(p0.y + p1.y + p2.y + p3.y + bv.y, 0.f) + b2f(rv.y);
    float y2 = fmaxf(p0.z + p1.z + p2.z + p3.z + bv.z, 0.f) + b2f(rv.z);
    float y3 = fmaxf(p0.w + p1.w + p2.w + p3.w + bv.w, 0.f) + b2f(rv.w);
    float4 o; o.x = y0; o.y = y1; o.z = y2; o.w = y3;
    reinterpret_cast<float4*>(ln_in)[fi] = o;
    s += y0 + y1 + y2 + y3;
    sq += y0 * y0 + y1 * y1 + y2 * y2 + y3 * y3;
  }
  #pragma unroll
  for (int d = 1; d < 64; d <<= 1) { s += __shfl_xor(s, d); sq += __shfl_xor(sq, d); }
  __shared__ float red[8];
  int w = t >> 6, lane = t & 63;
  if (lane == 0) { red[w] = s; red[4 + w] = sq; }
  __syncthreads();
  if (t == 0) {
    part[blockIdx.x * 2 + 0] = red[0] + red[1] + red[2] + red[3];
    part[blockIdx.x * 2 + 1] = red[4] + red[5] + red[6] + red[7];
  }
}

// ---------------- GEMM: C[M][N] = A[M][K] * Bt[N][K]^T  (bf16 in, f32 acc) ----------------
// BM=BN=128, BK=32, 2-phase dbuf, 4 waves each 64x64 out.
// EPI 0: store bf16. EPI 1: relu(acc+bias) bf16. EPI 3: f32 partial (split-K via blockIdx.z).
#define BM 128
#define BN 128
#define BK 32

template<int EPI>
__global__ __launch_bounds__(256) void gemm_bt(
    const u16* __restrict__ A, const u16* __restrict__ Bt, void* __restrict__ Cv,
    const float* __restrict__ bias, int M, int N, int K)
{
  __shared__ __align__(16) u16 As[2][BM * BK];
  __shared__ __align__(16) u16 Bs[2][BN * BK];
  const int t = threadIdx.x;
  const int lane = t & 63, w = t >> 6;
  const int wr = w >> 1, wc = w & 1;
  const int l15 = lane & 15, lh = lane >> 4;
  const int m0 = blockIdx.y * BM, n0 = blockIdx.x * BN;
  const int Ksub = K / gridDim.z;
  const int Koff = blockIdx.z * Ksub;

  f32x4 acc[4][4];
  const f32x4 z4 = {0.f, 0.f, 0.f, 0.f};
  #pragma unroll
  for (int i = 0; i < 4; i++)
    #pragma unroll
    for (int j = 0; j < 4; j++) acc[i][j] = z4;

  const int ca = t, cb = t + 256;
  const u16* a0p = A + (size_t)(m0 + (ca >> 2)) * K + (ca & 3) * 8 + Koff;
  const u16* a1p = A + (size_t)(m0 + (cb >> 2)) * K + (cb & 3) * 8 + Koff;
  const u16* b0p = Bt + (size_t)(n0 + (ca >> 2)) * K + (ca & 3) * 8 + Koff;
  const u16* b1p = Bt + (size_t)(n0 + (cb >> 2)) * K + (cb & 3) * 8 + Koff;

  auto stage = [&](int buf, int k0) {
    GLL(a0p + k0, &As[buf][ca * 8]);
    GLL(a1p + k0, &As[buf][cb * 8]);
    GLL(b0p + k0, &Bs[buf][ca * 8]);
    GLL(b1p + k0, &Bs[buf][cb * 8]);
  };

  const int nt = Ksub / BK;
  stage(0, 0);
  __syncthreads();
  for (int it = 0; it < nt; ++it) {
    const int cur = it & 1;
    if (it + 1 < nt) stage(cur ^ 1, (it + 1) * BK);
    bf16x8 af[4], bfr[4];
    #pragma unroll
    for (int i = 0; i < 4; i++)
      af[i] = *reinterpret_cast<const bf16x8*>(&As[cur][(wr * 64 + i * 16 + l15) * BK + lh * 8]);
    #pragma unroll
    for (int j = 0; j < 4; j++)
      bfr[j] = *reinterpret_cast<const bf16x8*>(&Bs[cur][(wc * 64 + j * 16 + l15) * BK + lh * 8]);
    #pragma unroll
    for (int i = 0; i < 4; i++)
      #pragma unroll
      for (int j = 0; j < 4; j++)
        acc[i][j] = __builtin_amdgcn_mfma_f32_16x16x32_bf16(af[i], bfr[j], acc[i][j], 0, 0, 0);
    __syncthreads();
  }

  float* Pout = (float*)Cv + (size_t)blockIdx.z * M * N;
  #pragma unroll
  for (int i = 0; i < 4; i++) {
    int row_b = m0 + wr * 64 + i * 16 + lh * 4;
    #pragma unroll
    for (int j = 0; j < 4; j++) {
      int col = n0 + wc * 64 + j * 16 + l15;
      float bv = (EPI == 1) ? bias[col] : 0.f;
      #pragma unroll
      for (int r = 0; r < 4; r++) {
        size_t off = (size_t)(row_b + r) * N + col;
        float v = acc[i][j][r];
        if (EPI == 1) ((u16*)Cv)[off] = f2bf(fmaxf(v + bv, 0.f));
        else if (EPI == 3) Pout[off] = v;
        else ((u16*)Cv)[off] = f2bf(v);
      }
    }
  }
}

// ---------------- fused attention (flash-style, online softmax), QBLK=64 ----------------
__global__ __launch_bounds__(256) void attn_k(
    const u16* __restrict__ qkv, const float* __restrict__ mask, u16* __restrict__ out)
{
  const int qt = blockIdx.x;   // 0..7 (64 q rows each)
  const int h = blockIdx.y;    // 0..11
  const int b = blockIdx.z;    // 0..7
  __shared__ __align__(16) u16 Qs[64 * 64];
  __shared__ __align__(16) u16 Ks[64 * 72];
  __shared__ __align__(16) u16 Vt[64 * 72];
  __shared__ __align__(16) u16 Pw[4][16 * 72];
  const int t = threadIdx.x, lane = t & 63, w = t >> 6;
  const int l15 = lane & 15, lh = lane >> 4;

  #pragma unroll
  for (int p = 0; p < 2; p++) {
    int c = t + p * 256;
    const u16* src = qkv + (size_t)(b * NS + qt * 64 + (c >> 3)) * 2304 + h * 64 + (c & 7) * 8;
    GLL(src, Qs + c * 8);
  }
  __syncthreads();

  bf16x8 aq[2];
  #pragma unroll
  for (int kk = 0; kk < 2; kk++)
    aq[kk] = *reinterpret_cast<const bf16x8*>(&Qs[(w * 16 + l15) * 64 + kk * 32 + lh * 8]);

  float qm[4];
  #pragma unroll
  for (int r = 0; r < 4; r++)
    qm[r] = mask[b * NS + qt * 64 + w * 16 + lh * 4 + r] * 0.125f;

  float mrun[4], lrun[4];
  f32x4 o[4];
  const f32x4 z4 = {0.f, 0.f, 0.f, 0.f};
  #pragma unroll
  for (int r = 0; r < 4; r++) { mrun[r] = -3e38f; lrun[r] = 0.f; }
  #pragma unroll
  for (int jn = 0; jn < 4; jn++) o[jn] = z4;

  for (int kc = 0; kc < 8; kc++) {
    __syncthreads();
    #pragma unroll
    for (int p = 0; p < 2; p++) {
      int k = (t >> 3) + p * 32;
      int dh0 = (t & 7) * 8;
      const u16* ks = qkv + (size_t)(b * NS + kc * 64 + k) * 2304 + ND + h * 64 + dh0;
      uint4 kv4 = *reinterpret_cast<const uint4*>(ks);
      *reinterpret_cast<uint4*>(&Ks[k * 72 + dh0]) = kv4;
    }
    #pragma unroll
    for (int p = 0; p < 2; p++) {
      int k = (t >> 3) + p * 32;
      int dh0 = (t & 7) * 8;
      const u16* vs = qkv + (size_t)(b * NS + kc * 64 + k) * 2304 + 2 * ND + h * 64 + dh0;
      uint4 vv = *reinterpret_cast<const uint4*>(vs);
      Vt[(dh0 + 0) * 72 + k] = (u16)(vv.x & 0xffff);
      Vt[(dh0 + 1) * 72 + k] = (u16)(vv.x >> 16);
      Vt[(dh0 + 2) * 72 + k] = (u16)(vv.y & 0xffff);
      Vt[(dh0 + 3) * 72 + k] = (u16)(vv.y >> 16);
      Vt[(dh0 + 4) * 72 + k] = (u16)(vv.z & 0xffff);
      Vt[(dh0 + 5) * 72 + k] = (u16)(vv.z >> 16);
      Vt[(dh0 + 6) * 72 + k] = (u16)(vv.w & 0xffff);
      Vt[(dh0 + 7) * 72 + k] = (u16)(vv.w >> 16);
    }
    __syncthreads();

    f32x4 s[4];
    #pragma unroll
    for (int j = 0; j < 4; j++) s[j] = z4;
    #pragma unroll
    for (int kk = 0; kk < 2; kk++) {
      bf16x8 bk[4];
      #pragma unroll
      for (int j = 0; j < 4; j++)
        bk[j] = *reinterpret_cast<const bf16x8*>(&Ks[(j * 16 + l15) * 72 + kk * 32 + lh * 8]);
      #pragma unroll
      for (int j = 0; j < 4; j++)
        s[j] = __builtin_amdgcn_mfma_f32_16x16x32_bf16(aq[kk], bk[j], s[j], 0, 0, 0);
    }

    #pragma unroll
    for (int r = 0; r < 4; r++) {
      float q4 = qm[r];
      float v0 = s[0][r] * q4, v1 = s[1][r] * q4, v2 = s[2][r] * q4, v3 = s[3][r] * q4;
      float pm = fmaxf(fmaxf(v0, v1), fmaxf(v2, v3));
      pm = fmaxf(pm, __shfl_xor(pm, 1));
      pm = fmaxf(pm, __shfl_xor(pm, 2));
      pm = fmaxf(pm, __shfl_xor(pm, 4));
      pm = fmaxf(pm, __shfl_xor(pm, 8));
      float mnew = fmaxf(mrun[r], pm);
      float corr = __expf(mrun[r] - mnew);
      mrun[r] = mnew;
      float p0 = __expf(v0 - mnew), p1 = __expf(v1 - mnew);
      float p2 = __expf(v2 - mnew), p3 = __expf(v3 - mnew);
      s[0][r] = p0; s[1][r] = p1; s[2][r] = p2; s[3][r] = p3;
      float rs = p0 + p1 + p2 + p3;
      rs += __shfl_xor(rs, 1);
      rs += __shfl_xor(rs, 2);
      rs += __shfl_xor(rs, 4);
      rs += __shfl_xor(rs, 8);
      lrun[r] = lrun[r] * corr + rs;
      #pragma unroll
      for (int jn = 0; jn < 4; jn++) o[jn][r] *= corr;
    }
    #pragma unroll
    for (int j = 0; j < 4; j++)
      #pragma unroll
      for (int r = 0; r < 4; r++)
        Pw[w][(lh * 4 + r) * 72 + j * 16 + l15] = f2bf(s[j][r]);

    #pragma unroll
    for (int kk2 = 0; kk2 < 2; kk2++) {
      bf16x8 pa, vb[4];
      pa = *reinterpret_cast<const bf16x8*>(&Pw[w][l15 * 72 + kk2 * 32 + lh * 8]);
      #pragma unroll
      for (int jn = 0; jn < 4; jn++)
        vb[jn] = *reinterpret_cast<const bf16x8*>(&Vt[(jn * 16 + l15) * 72 + kk2 * 32 + lh * 8]);
      #pragma unroll
      for (int jn = 0; jn < 4; jn++)
        o[jn] = __builtin_amdgcn_mfma_f32_16x16x32_bf16(pa, vb[jn], o[jn], 0, 0, 0);
    }
  }

  #pragma unroll
  for (int r = 0; r < 4; r++) {
    int q = qt * 64 + w * 16 + lh * 4 + r;
    float invl = 1.f / lrun[r];
    #pragma unroll
    for (int jn = 0; jn < 4; jn++) {
      int col = h * 64 + jn * 16 + l15;
      out[(size_t)(b * NS + q) * ND + col] = f2bf(o[jn][r] * invl);
    }
  }
}

// ---------------- final logits (reads bf16 x) ----------------
__global__ __launch_bounds__(256) void logits_k(const u16* __restrict__ x,
    const float* __restrict__ Wp, const float* __restrict__ bp, const float* __restrict__ mask,
    float* __restrict__ out)
{
  int t = threadIdx.x, lane = t & 63, w = t >> 6;
  int row = blockIdx.x * 4 + w;
  const u16* xr = x + (size_t)row * ND;
  float a0 = 0.f, a1 = 0.f;
  for (int i = lane; i < ND; i += 64) {
    float v = b2f(xr[i]);
    a0 += v * Wp[i * 2 + 0];
    a1 += v * Wp[i * 2 + 1];
  }
  #pragma unroll
  for (int d = 1; d < 64; d <<= 1) { a0 += __shfl_xor(a0, d); a1 += __shfl_xor(a1, d); }
  if (lane == 0) {
    float pen = (1.f - mask[row]) * -10000.f;
    out[row] = a0 + bp[0] + pen;
    out[NROWS + row] = a1 + bp[1] + pen;
  }
}

extern "C" void kernel_launch(void* const* d_in, const int* in_sizes, int n_in,
                              void* d_out, int out_size, void* d_ws, size_t ws_size,
                              hipStream_t stream)
{
  const int* ids = (const int*)d_in[0];
  const int* segs = (const int*)d_in[1];
  const float* mask = (const float*)d_in[2];
  const float* wemb = (const float*)d_in[3];
  const float* semb = (const float*)d_in[4];
  const float* pemb = (const float*)d_in[5];
  const float* ln0g = (const float*)d_in[6];
  const float* ln0b = (const float*)d_in[7];
  const float* Wq = (const float*)d_in[8];
  const float* Wk = (const float*)d_in[9];
  const float* Wv = (const float*)d_in[10];
  const float* W1 = (const float*)d_in[11];
  const float* b1 = (const float*)d_in[12];
  const float* Wi = (const float*)d_in[13];
  const float* bi = (const float*)d_in[14];
  const float* W2 = (const float*)d_in[15];
  const float* b2 = (const float*)d_in[16];
  const float* lng = (const float*)d_in[17];
  const float* lnb = (const float*)d_in[18];
  const float* Wp = (const float*)d_in[19];
  const float* bp = (const float*)d_in[20];

  char* ws = (char*)d_ws;
  size_t o = 0;
  auto alloc = [&](size_t n) { size_t r = o; o += (n + 255) & ~(size_t)255; return r; };
  u16* wqkv_t = (u16*)(ws + alloc((size_t)NL * 2304 * ND * 2));
  u16* w1_t   = (u16*)(ws + alloc((size_t)NL * ND * ND * 2));
  u16* wi_t   = (u16*)(ws + alloc((size_t)NL * ND * NI * 2));
  u16* w2_t   = (u16*)(ws + alloc((size_t)NL * ND * NI * 2));
  u16* x_bf16  = (u16*)(ws + alloc((size_t)NROWS * ND * 2));
  u16* qkv     = (u16*)(ws + alloc((size_t)NROWS * 2304 * 2));
  u16* attn    = (u16*)(ws + alloc((size_t)NROWS * ND * 2));
  u16* h1      = (u16*)(ws + alloc((size_t)NROWS * ND * 2));
  u16* hi      = (u16*)(ws + alloc((size_t)NROWS * NI * 2));
  float* ln_in = (float*)(ws + alloc((size_t)NROWS * ND * 4));
  float* pbuf  = (float*)(ws + alloc(4 * MN * 4));
  float* part  = (float*)(ws + alloc(512 * 2 * 4));

  wconv_k<<<NL * 864, 256, 0, stream>>>(Wq, Wk, Wv, W1, Wi, W2, wqkv_t, w1_t, wi_t, w2_t);
  embed_ln_k<<<512, 256, 0, stream>>>(ids, segs, wemb, semb, pemb, ln_in, part);
  ln_apply_k<<<3072, 256, 0, stream>>>(ln_in, ln0g, ln0b, part, x_bf16);

  for (int l = 0; l < NL; l++) {
    gemm_bt<0><<<dim3(18, 32), 256, 0, stream>>>(x_bf16, wqkv_t + (size_t)l * 2304 * ND, qkv,
                                                 nullptr, NROWS, 2304, ND);
    attn_k<<<dim3(8, NH, NB), 256, 0, stream>>>(qkv, mask, attn);
    gemm_bt<3><<<dim3(6, 32, 4), 256, 0, stream>>>(attn, w1_t + (size_t)l * ND * ND, pbuf,
                                                   nullptr, NROWS, ND, ND);
    finw1_k<<<3072, 256, 0, stream>>>(pbuf, b1 + (size_t)l * ND, h1);
    gemm_bt<1><<<dim3(24, 32), 256, 0, stream>>>(h1, wi_t + (size_t)l * ND * NI, hi,
                                                 bi + (size_t)l * NI, NROWS, NI, ND);
    gemm_bt<3><<<dim3(6, 32, 4), 256, 0, stream>>>(hi, w2_t + (size_t)l * ND * NI, pbuf,
                                                   nullptr, NROWS, ND, NI);
    finw2_k<<<512, 256, 0, stream>>>(pbuf, b2 + (size_t)l * ND, x_bf16, ln_in, part);
    ln_apply_k<<<3072, 256, 0, stream>>>(ln_in, lng + (size_t)l * SD, lnb + (size_t)l * SD, part, x_bf16);
  }

  logits_k<<<1024, 256, 0, stream>>>(x_bf16, Wp, bp, mask, (float*)d_out);
}

// Round 12
// 976.305 us; speedup vs baseline: 1.1738x; 1.1416x over previous
//
#include <hip/hip_runtime.h>
#include <cstdint>
#include <cstddef>

typedef __bf16 bf16x8 __attribute__((ext_vector_type(8)));
typedef float f32x4 __attribute__((ext_vector_type(4)));
typedef unsigned short u16;

#define NB 8
#define NS 512
#define ND 768
#define NH 12
#define NL 6
#define NI 3072
#define NROWS (NB*NS)      // 4096
#define SD (NS*ND)         // 393216
#define MN ((size_t)NROWS*ND)  // 3145728

__device__ __forceinline__ u16 f2bf(float f) {
  union { float f; unsigned u; } v; v.f = f;
  unsigned r = v.u + 0x7fffu + ((v.u >> 16) & 1u);
  return (u16)(r >> 16);
}
__device__ __forceinline__ float b2f(u16 u) {
  union { unsigned u; float f; } v; v.u = ((unsigned)u) << 16; return v.f;
}

#define GLL(gsrc, ldst) \
  __builtin_amdgcn_global_load_lds((__attribute__((address_space(1))) void*)(gsrc), \
                                   (__attribute__((address_space(3))) void*)(ldst), 16, 0, 0)

// ---------------- weight transpose+convert (FROZEN: ~77us structural plateau) ----------------
#define CHS 4168   // u16 stride per 64x65 chunk (+8 pad)

__global__ __launch_bounds__(256) void wconv_k(
    const float* __restrict__ Wq, const float* __restrict__ Wk, const float* __restrict__ Wv,
    const float* __restrict__ W1, const float* __restrict__ Wi, const float* __restrict__ W2,
    u16* __restrict__ wqkv_t, u16* __restrict__ w1_t, u16* __restrict__ wi_t, u16* __restrict__ w2_t)
{
  int bid = blockIdx.x;
  int l = bid / 864, r = bid % 864;
  const float* src; u16* dst; int Csrc, dstLD, tr, tc;
  if (r < 216) {
    int which = r / 72, t2 = r % 72;
    src = (which == 0 ? Wq : (which == 1 ? Wk : Wv)) + (size_t)l * ND * ND;
    dst = wqkv_t + (size_t)l * 2304 * ND + (size_t)which * ND * ND;
    Csrc = ND; dstLD = ND; tr = t2 / 12; tc = t2 % 12;
  } else if (r < 288) {
    int t2 = r - 216;
    src = W1 + (size_t)l * ND * ND; dst = w1_t + (size_t)l * ND * ND;
    Csrc = ND; dstLD = ND; tr = t2 / 12; tc = t2 % 12;
  } else if (r < 576) {
    int t2 = r - 288;
    src = Wi + (size_t)l * ND * NI; dst = wi_t + (size_t)l * ND * NI;
    Csrc = NI; dstLD = ND; tr = t2 / 48; tc = t2 % 48;
  } else {
    int t2 = r - 576;
    src = W2 + (size_t)l * ND * NI; dst = w2_t + (size_t)l * ND * NI;
    Csrc = ND; dstLD = NI; tr = t2 / 12; tc = t2 % 12;
  }
  __shared__ u16 lds[2 * CHS];
  int t0 = threadIdx.x;
  {
    int rrow = t0 >> 3, c0 = (t0 & 7) * 8;
    float4 va[4], vb[4];
    #pragma unroll
    for (int q = 0; q < 4; q++) {
      const float* sp = src + (size_t)(tr * 128 + q * 32 + rrow) * Csrc + tc * 64 + c0;
      va[q] = *reinterpret_cast<const float4*>(sp);
      vb[q] = *reinterpret_cast<const float4*>(sp + 4);
    }
    #pragma unroll
    for (int q = 0; q < 4; q++) {
      int row = q * 32 + rrow;
      u16* lp = &lds[(row >> 6) * CHS + (row & 63) * 65 + c0];
      lp[0] = f2bf(va[q].x); lp[1] = f2bf(va[q].y); lp[2] = f2bf(va[q].z); lp[3] = f2bf(va[q].w);
      lp[4] = f2bf(vb[q].x); lp[5] = f2bf(vb[q].y); lp[6] = f2bf(vb[q].z); lp[7] = f2bf(vb[q].w);
    }
  }
  __syncthreads();
  {
    int qq = t0 & 15;
    int rb = t0 >> 4;
    int ch = qq >> 3;
    int r6b = (qq & 7) * 8;
    #pragma unroll
    for (int p = 0; p < 4; p++) {
      int dstrow = p * 16 + rb;
      const u16* lq = &lds[ch * CHS + dstrow];
      unsigned res[4];
      #pragma unroll
      for (int e = 0; e < 4; e++) {
        unsigned lo = lq[(r6b + 2 * e) * 65];
        unsigned hi = lq[(r6b + 2 * e + 1) * 65];
        res[e] = lo | (hi << 16);
      }
      u16* dp = dst + (size_t)(tc * 64 + dstrow) * dstLD + tr * 128 + qq * 8;
      *reinterpret_cast<uint4*>(dp) = make_uint4(res[0], res[1], res[2], res[3]);
    }
  }
}

// ---------------- embedding sum -> f32, fused LN partial sums ----------------
__global__ __launch_bounds__(256) void embed_ln_k(const int* __restrict__ ids,
    const int* __restrict__ segs, const float* __restrict__ wemb,
    const float* __restrict__ semb, const float* __restrict__ pemb,
    float* __restrict__ out, float* __restrict__ part)
{
  int b = blockIdx.x >> 6, c = blockIdx.x & 63;
  int base_row = b * NS + c * 8;
  int t = threadIdx.x;
  float s = 0.f, sq = 0.f;
  #pragma unroll
  for (int j = 0; j < 6; j++) {
    int fi = t + j * 256;
    int riw = fi / 192, col4 = fi - riw * 192;
    int row = base_row + riw;
    int id = ids[row], sg = segs[row];
    int srow = row & (NS - 1);
    float4 a = reinterpret_cast<const float4*>(wemb + (size_t)id * ND)[col4];
    float4 bb = reinterpret_cast<const float4*>(semb + (size_t)sg * ND)[col4];
    float4 cc = reinterpret_cast<const float4*>(pemb + (size_t)srow * ND)[col4];
    float y0 = a.x + bb.x + cc.x, y1 = a.y + bb.y + cc.y;
    float y2 = a.z + bb.z + cc.z, y3 = a.w + bb.w + cc.w;
    float4 o; o.x = y0; o.y = y1; o.z = y2; o.w = y3;
    reinterpret_cast<float4*>(out)[(size_t)row * 192 + col4] = o;
    s += y0 + y1 + y2 + y3;
    sq += y0 * y0 + y1 * y1 + y2 * y2 + y3 * y3;
  }
  #pragma unroll
  for (int d = 1; d < 64; d <<= 1) { s += __shfl_xor(s, d); sq += __shfl_xor(sq, d); }
  __shared__ float red[8];
  int w = t >> 6, lane = t & 63;
  if (lane == 0) { red[w] = s; red[4 + w] = sq; }
  __syncthreads();
  if (t == 0) {
    part[blockIdx.x * 2 + 0] = red[0] + red[1] + red[2] + red[3];
    part[blockIdx.x * 2 + 1] = red[4] + red[5] + red[6] + red[7];
  }
}

// ---------------- LN apply (fused final reduce of part[]) -> bf16 ----------------
__global__ __launch_bounds__(256) void ln_apply_k(const float* __restrict__ x,
    const float* __restrict__ g, const float* __restrict__ bta, const float* __restrict__ part,
    u16* __restrict__ xb)
{
  int idx = blockIdx.x * 256 + threadIdx.x;
  int e = idx * 4;
  int b = e / SD;
  int sd = e - b * SD;
  int lane = threadIdx.x & 63;
  float s = part[b * 128 + lane * 2 + 0];
  float q = part[b * 128 + lane * 2 + 1];
  #pragma unroll
  for (int d = 1; d < 64; d <<= 1) { s += __shfl_xor(s, d); q += __shfl_xor(q, d); }
  float inv = 1.f / (float)SD;
  float mu = s * inv;
  float rstd = rsqrtf(q * inv - mu * mu + 1e-5f);
  float4 v = reinterpret_cast<const float4*>(x)[idx];
  float4 gg = reinterpret_cast<const float4*>(g)[sd >> 2];
  float4 bb = reinterpret_cast<const float4*>(bta)[sd >> 2];
  float y0 = (v.x - mu) * rstd * gg.x + bb.x;
  float y1 = (v.y - mu) * rstd * gg.y + bb.y;
  float y2 = (v.z - mu) * rstd * gg.z + bb.z;
  float y3 = (v.w - mu) * rstd * gg.w + bb.w;
  reinterpret_cast<ushort4*>(xb)[idx] = make_ushort4(f2bf(y0), f2bf(y1), f2bf(y2), f2bf(y3));
}

// ---------------- W1 finalize: sum 4 bf16 K-partials + bias, relu -> bf16 ----------------
__global__ __launch_bounds__(256) void finw1_k(const u16* __restrict__ P,
    const float* __restrict__ bias, u16* __restrict__ out)
{
  size_t idx = (size_t)blockIdx.x * 256 + threadIdx.x;  // ushort4 index, MN/4 total
  ushort4 p0 = reinterpret_cast<const ushort4*>(P)[idx];
  ushort4 p1 = reinterpret_cast<const ushort4*>(P)[idx + (MN >> 2)];
  ushort4 p2 = reinterpret_cast<const ushort4*>(P)[idx + 2 * (MN >> 2)];
  ushort4 p3 = reinterpret_cast<const ushort4*>(P)[idx + 3 * (MN >> 2)];
  int col4 = (int)((idx * 4) % ND) >> 2;
  float4 bv = reinterpret_cast<const float4*>(bias)[col4];
  float y0 = fmaxf(b2f(p0.x) + b2f(p1.x) + b2f(p2.x) + b2f(p3.x) + bv.x, 0.f);
  float y1 = fmaxf(b2f(p0.y) + b2f(p1.y) + b2f(p2.y) + b2f(p3.y) + bv.y, 0.f);
  float y2 = fmaxf(b2f(p0.z) + b2f(p1.z) + b2f(p2.z) + b2f(p3.z) + bv.z, 0.f);
  float y3 = fmaxf(b2f(p0.w) + b2f(p1.w) + b2f(p2.w) + b2f(p3.w) + bv.w, 0.f);
  reinterpret_cast<ushort4*>(out)[idx] = make_ushort4(f2bf(y0), f2bf(y1), f2bf(y2), f2bf(y3));
}

// ---------------- W2 finalize: 4 bf16 partials + bias, relu, + bf16 resid -> ln_in f32, LN partial ----
__global__ __launch_bounds__(256) void finw2_k(const u16* __restrict__ P,
    const float* __restrict__ bias, const u16* __restrict__ resid,
    float* __restrict__ ln_in, float* __restrict__ part)
{
  int b = blockIdx.x >> 6, c = blockIdx.x & 63;
  size_t f4base = ((size_t)b * SD + (size_t)c * 6144) >> 2;
  int t = threadIdx.x;
  float s = 0.f, sq = 0.f;
  #pragma unroll
  for (int j = 0; j < 6; j++) {
    size_t fi = f4base + t + j * 256;
    ushort4 p0 = reinterpret_cast<const ushort4*>(P)[fi];
    ushort4 p1 = reinterpret_cast<const ushort4*>(P)[fi + (MN >> 2)];
    ushort4 p2 = reinterpret_cast<const ushort4*>(P)[fi + 2 * (MN >> 2)];
    ushort4 p3 = reinterpret_cast<const ushort4*>(P)[fi + 3 * (MN >> 2)];
    ushort4 rv = reinterpret_cast<const ushort4*>(resid)[fi];
    int col4 = (((t + j * 256) * 4) % ND) >> 2;
    float4 bv = reinterpret_cast<const float4*>(bias)[col4];
    float y0 = fmaxf(b2f(p0.x) + b2f(p1.x) + b2f(p2.x) + b2f(p3.x) + bv.x, 0.f) + b2f(rv.x);
    float y1 = fmaxf(b2f(p0.y) + b2f(p1.y) + b2f(p2.y) + b2f(p3.y) + bv.y, 0.f) + b2f(rv.y);
    float y2 = fmaxf(b2f(p0.z) + b2f(p1.z) + b2f(p2.z) + b2f(p3.z) + bv.z, 0.f) + b2f(rv.z);
    float y3 = fmaxf(b2f(p0.w) + b2f(p1.w) + b2f(p2.w) + b2f(p3.w) + bv.w, 0.f) + b2f(rv.w);
    float4 o; o.x = y0; o.y = y1; o.z = y2; o.w = y3;
    reinterpret_cast<float4*>(ln_in)[fi] = o;
    s += y0 + y1 + y2 + y3;
    sq += y0 * y0 + y1 * y1 + y2 * y2 + y3 * y3;
  }
  #pragma unroll
  for (int d = 1; d < 64; d <<= 1) { s += __shfl_xor(s, d); sq += __shfl_xor(sq, d); }
  __shared__ float red[8];
  int w = t >> 6, lane = t & 63;
  if (lane == 0) { red[w] = s; red[4 + w] = sq; }
  __syncthreads();
  if (t == 0) {
    part[blockIdx.x * 2 + 0] = red[0] + red[1] + red[2] + red[3];
    part[blockIdx.x * 2 + 1] = red[4] + red[5] + red[6] + red[7];
  }
}

// ---------------- GEMM: C[M][N] = A[M][K] * Bt[N][K]^T  (bf16 in, f32 acc) ----------------
// BM=BN=128, BK=32, 2-phase dbuf. XCD-aware bijective swizzle (grid always %8==0):
// logical L = (wg&7)*(nwg/8)+(wg>>3) -> consecutive logical tiles (sharing A/B panels)
// land on the same XCD's L2. EPI 0: bf16. EPI 1: relu+bias bf16. EPI 3: bf16 partial (split-K).
#define BM 128
#define BN 128
#define BK 32

template<int EPI>
__global__ __launch_bounds__(256) void gemm_bt(
    const u16* __restrict__ A, const u16* __restrict__ Bt, void* __restrict__ Cv,
    const float* __restrict__ bias, int M, int N, int K)
{
  __shared__ __align__(16) u16 As[2][BM * BK];
  __shared__ __align__(16) u16 Bs[2][BN * BK];
  const int gx = gridDim.x, gy = gridDim.y;
  int wg = (blockIdx.z * gy + blockIdx.y) * gx + blockIdx.x;
  int nwg = gx * gy * gridDim.z;
  int L = (wg & 7) * (nwg >> 3) + (wg >> 3);
  const int bx = L % gx, by = (L / gx) % gy, bz = L / (gx * gy);

  const int t = threadIdx.x;
  const int lane = t & 63, w = t >> 6;
  const int wr = w >> 1, wc = w & 1;
  const int l15 = lane & 15, lh = lane >> 4;
  const int m0 = by * BM, n0 = bx * BN;
  const int Ksub = K / gridDim.z;
  const int Koff = bz * Ksub;

  f32x4 acc[4][4];
  const f32x4 z4 = {0.f, 0.f, 0.f, 0.f};
  #pragma unroll
  for (int i = 0; i < 4; i++)
    #pragma unroll
    for (int j = 0; j < 4; j++) acc[i][j] = z4;

  const int ca = t, cb = t + 256;
  const u16* a0p = A + (size_t)(m0 + (ca >> 2)) * K + (ca & 3) * 8 + Koff;
  const u16* a1p = A + (size_t)(m0 + (cb >> 2)) * K + (cb & 3) * 8 + Koff;
  const u16* b0p = Bt + (size_t)(n0 + (ca >> 2)) * K + (ca & 3) * 8 + Koff;
  const u16* b1p = Bt + (size_t)(n0 + (cb >> 2)) * K + (cb & 3) * 8 + Koff;

  auto stage = [&](int buf, int k0) {
    GLL(a0p + k0, &As[buf][ca * 8]);
    GLL(a1p + k0, &As[buf][cb * 8]);
    GLL(b0p + k0, &Bs[buf][ca * 8]);
    GLL(b1p + k0, &Bs[buf][cb * 8]);
  };

  const int nt = Ksub / BK;
  stage(0, 0);
  __syncthreads();
  for (int it = 0; it < nt; ++it) {
    const int cur = it & 1;
    if (it + 1 < nt) stage(cur ^ 1, (it + 1) * BK);
    bf16x8 af[4], bfr[4];
    #pragma unroll
    for (int i = 0; i < 4; i++)
      af[i] = *reinterpret_cast<const bf16x8*>(&As[cur][(wr * 64 + i * 16 + l15) * BK + lh * 8]);
    #pragma unroll
    for (int j = 0; j < 4; j++)
      bfr[j] = *reinterpret_cast<const bf16x8*>(&Bs[cur][(wc * 64 + j * 16 + l15) * BK + lh * 8]);
    #pragma unroll
    for (int i = 0; i < 4; i++)
      #pragma unroll
      for (int j = 0; j < 4; j++)
        acc[i][j] = __builtin_amdgcn_mfma_f32_16x16x32_bf16(af[i], bfr[j], acc[i][j], 0, 0, 0);
    __syncthreads();
  }

  u16* PoutB = (u16*)Cv + (size_t)bz * M * N;
  #pragma unroll
  for (int i = 0; i < 4; i++) {
    int row_b = m0 + wr * 64 + i * 16 + lh * 4;
    #pragma unroll
    for (int j = 0; j < 4; j++) {
      int col = n0 + wc * 64 + j * 16 + l15;
      float bv = (EPI == 1) ? bias[col] : 0.f;
      #pragma unroll
      for (int r = 0; r < 4; r++) {
        size_t off = (size_t)(row_b + r) * N + col;
        float v = acc[i][j][r];
        if (EPI == 1) ((u16*)Cv)[off] = f2bf(fmaxf(v + bv, 0.f));
        else if (EPI == 3) PoutB[off] = f2bf(v);
        else ((u16*)Cv)[off] = f2bf(v);
      }
    }
  }
}

// ---------------- fused attention (flash-style, online softmax), QBLK=64, XCD swizzle ----------------
__global__ __launch_bounds__(256) void attn_k(
    const u16* __restrict__ qkv, const float* __restrict__ mask, u16* __restrict__ out)
{
  int wg = (blockIdx.z * 12 + blockIdx.y) * 8 + blockIdx.x;   // 768 total
  int L = (wg & 7) * 96 + (wg >> 3);
  const int qt = L & 7;
  const int h = (L >> 3) % 12;
  const int b = L / 96;
  __shared__ __align__(16) u16 Qs[64 * 64];
  __shared__ __align__(16) u16 Ks[64 * 72];
  __shared__ __align__(16) u16 Vt[64 * 72];
  __shared__ __align__(16) u16 Pw[4][16 * 72];
  const int t = threadIdx.x, lane = t & 63, w = t >> 6;
  const int l15 = lane & 15, lh = lane >> 4;

  #pragma unroll
  for (int p = 0; p < 2; p++) {
    int c = t + p * 256;
    const u16* src = qkv + (size_t)(b * NS + qt * 64 + (c >> 3)) * 2304 + h * 64 + (c & 7) * 8;
    GLL(src, Qs + c * 8);
  }
  __syncthreads();

  bf16x8 aq[2];
  #pragma unroll
  for (int kk = 0; kk < 2; kk++)
    aq[kk] = *reinterpret_cast<const bf16x8*>(&Qs[(w * 16 + l15) * 64 + kk * 32 + lh * 8]);

  float qm[4];
  #pragma unroll
  for (int r = 0; r < 4; r++)
    qm[r] = mask[b * NS + qt * 64 + w * 16 + lh * 4 + r] * 0.125f;

  float mrun[4], lrun[4];
  f32x4 o[4];
  const f32x4 z4 = {0.f, 0.f, 0.f, 0.f};
  #pragma unroll
  for (int r = 0; r < 4; r++) { mrun[r] = -3e38f; lrun[r] = 0.f; }
  #pragma unroll
  for (int jn = 0; jn < 4; jn++) o[jn] = z4;

  for (int kc = 0; kc < 8; kc++) {
    __syncthreads();
    #pragma unroll
    for (int p = 0; p < 2; p++) {
      int k = (t >> 3) + p * 32;
      int dh0 = (t & 7) * 8;
      const u16* ks = qkv + (size_t)(b * NS + kc * 64 + k) * 2304 + ND + h * 64 + dh0;
      uint4 kv4 = *reinterpret_cast<const uint4*>(ks);
      *reinterpret_cast<uint4*>(&Ks[k * 72 + dh0]) = kv4;
    }
    #pragma unroll
    for (int p = 0; p < 2; p++) {
      int k = (t >> 3) + p * 32;
      int dh0 = (t & 7) * 8;
      const u16* vs = qkv + (size_t)(b * NS + kc * 64 + k) * 2304 + 2 * ND + h * 64 + dh0;
      uint4 vv = *reinterpret_cast<const uint4*>(vs);
      Vt[(dh0 + 0) * 72 + k] = (u16)(vv.x & 0xffff);
      Vt[(dh0 + 1) * 72 + k] = (u16)(vv.x >> 16);
      Vt[(dh0 + 2) * 72 + k] = (u16)(vv.y & 0xffff);
      Vt[(dh0 + 3) * 72 + k] = (u16)(vv.y >> 16);
      Vt[(dh0 + 4) * 72 + k] = (u16)(vv.z & 0xffff);
      Vt[(dh0 + 5) * 72 + k] = (u16)(vv.z >> 16);
      Vt[(dh0 + 6) * 72 + k] = (u16)(vv.w & 0xffff);
      Vt[(dh0 + 7) * 72 + k] = (u16)(vv.w >> 16);
    }
    __syncthreads();

    f32x4 s[4];
    #pragma unroll
    for (int j = 0; j < 4; j++) s[j] = z4;
    #pragma unroll
    for (int kk = 0; kk < 2; kk++) {
      bf16x8 bk[4];
      #pragma unroll
      for (int j = 0; j < 4; j++)
        bk[j] = *reinterpret_cast<const bf16x8*>(&Ks[(j * 16 + l15) * 72 + kk * 32 + lh * 8]);
      #pragma unroll
      for (int j = 0; j < 4; j++)
        s[j] = __builtin_amdgcn_mfma_f32_16x16x32_bf16(aq[kk], bk[j], s[j], 0, 0, 0);
    }

    #pragma unroll
    for (int r = 0; r < 4; r++) {
      float q4 = qm[r];
      float v0 = s[0][r] * q4, v1 = s[1][r] * q4, v2 = s[2][r] * q4, v3 = s[3][r] * q4;
      float pm = fmaxf(fmaxf(v0, v1), fmaxf(v2, v3));
      pm = fmaxf(pm, __shfl_xor(pm, 1));
      pm = fmaxf(pm, __shfl_xor(pm, 2));
      pm = fmaxf(pm, __shfl_xor(pm, 4));
      pm = fmaxf(pm, __shfl_xor(pm, 8));
      float mnew = fmaxf(mrun[r], pm);
      float corr = __expf(mrun[r] - mnew);
      mrun[r] = mnew;
      float p0 = __expf(v0 - mnew), p1 = __expf(v1 - mnew);
      float p2 = __expf(v2 - mnew), p3 = __expf(v3 - mnew);
      s[0][r] = p0; s[1][r] = p1; s[2][r] = p2; s[3][r] = p3;
      float rs = p0 + p1 + p2 + p3;
      rs += __shfl_xor(rs, 1);
      rs += __shfl_xor(rs, 2);
      rs += __shfl_xor(rs, 4);
      rs += __shfl_xor(rs, 8);
      lrun[r] = lrun[r] * corr + rs;
      #pragma unroll
      for (int jn = 0; jn < 4; jn++) o[jn][r] *= corr;
    }
    #pragma unroll
    for (int j = 0; j < 4; j++)
      #pragma unroll
      for (int r = 0; r < 4; r++)
        Pw[w][(lh * 4 + r) * 72 + j * 16 + l15] = f2bf(s[j][r]);

    #pragma unroll
    for (int kk2 = 0; kk2 < 2; kk2++) {
      bf16x8 pa, vb[4];
      pa = *reinterpret_cast<const bf16x8*>(&Pw[w][l15 * 72 + kk2 * 32 + lh * 8]);
      #pragma unroll
      for (int jn = 0; jn < 4; jn++)
        vb[jn] = *reinterpret_cast<const bf16x8*>(&Vt[(jn * 16 + l15) * 72 + kk2 * 32 + lh * 8]);
      #pragma unroll
      for (int jn = 0; jn < 4; jn++)
        o[jn] = __builtin_amdgcn_mfma_f32_16x16x32_bf16(pa, vb[jn], o[jn], 0, 0, 0);
    }
  }

  #pragma unroll
  for (int r = 0; r < 4; r++) {
    int q = qt * 64 + w * 16 + lh * 4 + r;
    float invl = 1.f / lrun[r];
    #pragma unroll
    for (int jn = 0; jn < 4; jn++) {
      int col = h * 64 + jn * 16 + l15;
      out[(size_t)(b * NS + q) * ND + col] = f2bf(o[jn][r] * invl);
    }
  }
}

// ---------------- final logits (reads bf16 x) ----------------
__global__ __launch_bounds__(256) void logits_k(const u16* __restrict__ x,
    const float* __restrict__ Wp, const float* __restrict__ bp, const float* __restrict__ mask,
    float* __restrict__ out)
{
  int t = threadIdx.x, lane = t & 63, w = t >> 6;
  int row = blockIdx.x * 4 + w;
  const u16* xr = x + (size_t)row * ND;
  float a0 = 0.f, a1 = 0.f;
  for (int i = lane; i < ND; i += 64) {
    float v = b2f(xr[i]);
    a0 += v * Wp[i * 2 + 0];
    a1 += v * Wp[i * 2 + 1];
  }
  #pragma unroll
  for (int d = 1; d < 64; d <<= 1) { a0 += __shfl_xor(a0, d); a1 += __shfl_xor(a1, d); }
  if (lane == 0) {
    float pen = (1.f - mask[row]) * -10000.f;
    out[row] = a0 + bp[0] + pen;
    out[NROWS + row] = a1 + bp[1] + pen;
  }
}

extern "C" void kernel_launch(void* const* d_in, const int* in_sizes, int n_in,
                              void* d_out, int out_size, void* d_ws, size_t ws_size,
                              hipStream_t stream)
{
  const int* ids = (const int*)d_in[0];
  const int* segs = (const int*)d_in[1];
  const float* mask = (const float*)d_in[2];
  const float* wemb = (const float*)d_in[3];
  const float* semb = (const float*)d_in[4];
  const float* pemb = (const float*)d_in[5];
  const float* ln0g = (const float*)d_in[6];
  const float* ln0b = (const float*)d_in[7];
  const float* Wq = (const float*)d_in[8];
  const float* Wk = (const float*)d_in[9];
  const float* Wv = (const float*)d_in[10];
  const float* W1 = (const float*)d_in[11];
  const float* b1 = (const float*)d_in[12];
  const float* Wi = (const float*)d_in[13];
  const float* bi = (const float*)d_in[14];
  const float* W2 = (const float*)d_in[15];
  const float* b2 = (const float*)d_in[16];
  const float* lng = (const float*)d_in[17];
  const float* lnb = (const float*)d_in[18];
  const float* Wp = (const float*)d_in[19];
  const float* bp = (const float*)d_in[20];

  char* ws = (char*)d_ws;
  size_t o = 0;
  auto alloc = [&](size_t n) { size_t r = o; o += (n + 255) & ~(size_t)255; return r; };
  u16* wqkv_t = (u16*)(ws + alloc((size_t)NL * 2304 * ND * 2));
  u16* w1_t   = (u16*)(ws + alloc((size_t)NL * ND * ND * 2));
  u16* wi_t   = (u16*)(ws + alloc((size_t)NL * ND * NI * 2));
  u16* w2_t   = (u16*)(ws + alloc((size_t)NL * ND * NI * 2));
  u16* x_bf16  = (u16*)(ws + alloc((size_t)NROWS * ND * 2));
  u16* qkv     = (u16*)(ws + alloc((size_t)NROWS * 2304 * 2));
  u16* attn    = (u16*)(ws + alloc((size_t)NROWS * ND * 2));
  u16* h1      = (u16*)(ws + alloc((size_t)NROWS * ND * 2));
  u16* hi      = (u16*)(ws + alloc((size_t)NROWS * NI * 2));
  float* ln_in = (float*)(ws + alloc((size_t)NROWS * ND * 4));
  u16* pbuf    = (u16*)(ws + alloc(4 * MN * 2));
  float* part  = (float*)(ws + alloc(512 * 2 * 4));

  wconv_k<<<NL * 864, 256, 0, stream>>>(Wq, Wk, Wv, W1, Wi, W2, wqkv_t, w1_t, wi_t, w2_t);
  embed_ln_k<<<512, 256, 0, stream>>>(ids, segs, wemb, semb, pemb, ln_in, part);
  ln_apply_k<<<3072, 256, 0, stream>>>(ln_in, ln0g, ln0b, part, x_bf16);

  for (int l = 0; l < NL; l++) {
    gemm_bt<0><<<dim3(18, 32), 256, 0, stream>>>(x_bf16, wqkv_t + (size_t)l * 2304 * ND, qkv,
                                                 nullptr, NROWS, 2304, ND);
    attn_k<<<dim3(8, NH, NB), 256, 0, stream>>>(qkv, mask, attn);
    gemm_bt<3><<<dim3(6, 32, 4), 256, 0, stream>>>(attn, w1_t + (size_t)l * ND * ND, pbuf,
                                                   nullptr, NROWS, ND, ND);
    finw1_k<<<3072, 256, 0, stream>>>(pbuf, b1 + (size_t)l * ND, h1);
    gemm_bt<1><<<dim3(24, 32), 256, 0, stream>>>(h1, wi_t + (size_t)l * ND * NI, hi,
                                                 bi + (size_t)l * NI, NROWS, NI, ND);
    gemm_bt<3><<<dim3(6, 32, 4), 256, 0, stream>>>(hi, w2_t + (size_t)l * ND * NI, pbuf,
                                                   nullptr, NROWS, ND, NI);
    finw2_k<<<512, 256, 0, stream>>>(pbuf, b2 + (size_t)l * ND, x_bf16, ln_in, part);
    ln_apply_k<<<3072, 256, 0, stream>>>(ln_in, lng + (size_t)l * SD, lnb + (size_t)l * SD, part, x_bf16);
  }

  logits_k<<<1024, 256, 0, stream>>>(x_bf16, Wp, bp, mask, (float*)d_out);
}